// Round 1
// baseline (605.225 us; speedup 1.0000x reference)
//
#include <hip/hip_runtime.h>

#define DEV __device__ __forceinline__

typedef __attribute__((ext_vector_type(8))) short bf16x8;
typedef __attribute__((ext_vector_type(4))) float f32x4;

// problem constants
// N=65536 tokens, 8 heads, head dim 32, feature dim 256, block 256, 256 blocks
static constexpr float QSCALE = 0.17677669529663687f; // 1/sqrt(32)

DEV unsigned short f2bf(float f) {
    union { float f; unsigned int u; } a; a.f = f;
    unsigned int r = (a.u + 0x7fffu + ((a.u >> 16) & 1u)) >> 16; // RNE
    return (unsigned short)r;
}
DEV float bf2f(unsigned short s) {
    union { unsigned int u; float f; } a; a.u = ((unsigned int)s) << 16;
    return a.f;
}
DEV int bucketof(float v) {
    int b = (int)(v * 65536.0f);
    b = b < 0 ? 0 : b;
    b = b > 65535 ? 65535 : b;
    return b;
}

// ---------------- sort: stable argsort of coords[:,0] ----------------
__global__ void khist(const float* coords, unsigned int* hist) {
    int i = blockIdx.x * 256 + threadIdx.x;
    atomicAdd(&hist[bucketof(coords[i * 3])], 1u);
}

__global__ void kscan1(const unsigned int* hist, unsigned int* excl, unsigned int* aux) {
    __shared__ unsigned int s[256];
    int tid = threadIdx.x;
    int g = blockIdx.x * 256 + tid;
    unsigned int v = hist[g];
    s[tid] = v; __syncthreads();
    for (int off = 1; off < 256; off <<= 1) {
        unsigned int t = (tid >= off) ? s[tid - off] : 0u;
        __syncthreads();
        s[tid] += t;
        __syncthreads();
    }
    excl[g] = s[tid] - v;           // exclusive within block
    if (tid == 255) aux[blockIdx.x] = s[255];
}

__global__ void kscan2(unsigned int* aux) {
    __shared__ unsigned int s[256];
    int tid = threadIdx.x;
    unsigned int v = aux[tid];
    s[tid] = v; __syncthreads();
    for (int off = 1; off < 256; off <<= 1) {
        unsigned int t = (tid >= off) ? s[tid - off] : 0u;
        __syncthreads();
        s[tid] += t;
        __syncthreads();
    }
    aux[tid] = s[tid] - v;          // exclusive
}

__global__ void kscan3(unsigned int* excl, const unsigned int* aux) {
    int g = blockIdx.x * 256 + threadIdx.x;
    excl[g] += aux[blockIdx.x];
}

__global__ void kscatter(const float* coords, unsigned int* excl, unsigned int* memb) {
    int i = blockIdx.x * 256 + threadIdx.x;
    int b = bucketof(coords[i * 3]);
    unsigned int pos = atomicAdd(&excl[b], 1u);  // order within bucket irrelevant
    memb[pos] = (unsigned int)i;
}

__global__ void krank(const float* coords, const unsigned int* excl,
                      const unsigned int* memb, unsigned int* order) {
    int i = blockIdx.x * 256 + threadIdx.x;
    int b = bucketof(coords[i * 3]);
    unsigned int start = (b == 0) ? 0u : excl[b - 1]; // post-scatter: excl[b-1] == orig excl[b]
    unsigned int end = excl[b];
    unsigned int ki = __float_as_uint(coords[i * 3]); // positive floats: bits are order-preserving
    unsigned int r = start;
    for (unsigned int s2 = start; s2 < end; ++s2) {
        unsigned int j = memb[s2];
        unsigned int kj = __float_as_uint(coords[j * 3]);
        if (kj < ki || (kj == ki && j < (unsigned int)i)) r++;  // stable tie-break
    }
    order[r] = (unsigned int)i;
}

// ---------------- w2[h][c] = mean over (d,j) of w_rpe[h*32+d][c*8+j]^2 ----------------
__global__ void kw2(const float* w_rpe, float* w2) {
    int p = blockIdx.x;          // p = h*2 + c, 16 blocks
    int h = p >> 1, c = p & 1;
    int tid = threadIdx.x;
    int d = tid >> 3, j = tid & 7;
    float v = w_rpe[(h * 32 + d) * 16 + c * 8 + j];
    float v2 = v * v;
    for (int m = 32; m >= 1; m >>= 1) v2 += __shfl_xor(v2, m);
    __shared__ float part[4];
    if ((tid & 63) == 0) part[tid >> 6] = v2;
    __syncthreads();
    if (tid == 0) w2[p] = (part[0] + part[1] + part[2] + part[3]) * (1.0f / 256.0f);
}

// ---------------- LN1 + QKV projection -> bf16 [N][256], q pre-scaled by 1/sqrt(32) ---------
__global__ __launch_bounds__(256) void kproj(
    const float* x, const float* g1, const float* be1,
    const float* wq, const float* wk, const float* wv,
    unsigned short* qbf, unsigned short* kbf, unsigned short* vbf)
{
    __shared__ unsigned int stage[256][20];  // 32 bf16 (16 u32) per row, pad to 20 for banks/alignment
    int tid = threadIdx.x;
    int rt = blockIdx.x & 255;
    int half = blockIdx.x >> 8;              // 0: q heads 0-7 + k heads 0-3 ; 1: k heads 4-7 + v heads 0-7
    int row = rt * 256 + tid;

    float xv[32];
    const float4* xr = (const float4*)(x + (size_t)row * 32);
#pragma unroll
    for (int q4 = 0; q4 < 8; q4++) {
        float4 t = xr[q4];
        xv[q4 * 4 + 0] = t.x; xv[q4 * 4 + 1] = t.y; xv[q4 * 4 + 2] = t.z; xv[q4 * 4 + 3] = t.w;
    }
    float mu = 0.f;
#pragma unroll
    for (int d = 0; d < 32; d++) mu += xv[d];
    mu *= (1.0f / 32.0f);
    float var = 0.f;
#pragma unroll
    for (int d = 0; d < 32; d++) { float c = xv[d] - mu; var += c * c; }
    var *= (1.0f / 32.0f);
    float rstd = rsqrtf(var + 1e-5f);
    float xn[32];
#pragma unroll
    for (int d = 0; d < 32; d++) xn[d] = (xv[d] - mu) * rstd * g1[d] + be1[d];

    for (int g = 0; g < 12; g++) {
        const float* w; unsigned short* dst; int hh; bool isq = false;
        if (half == 0) {
            if (g < 8) { w = wq; dst = qbf; hh = g; isq = true; }
            else       { w = wk; dst = kbf; hh = g - 8; }
        } else {
            if (g < 4) { w = wk; dst = kbf; hh = 4 + g; }
            else       { w = wv; dst = vbf; hh = g - 4; }
        }
        float scale = isq ? QSCALE : 1.0f;
        float prev = 0.f;
        for (int fd = 0; fd < 32; fd++) {
            float a = 0.f;
            const float* wrow = w + (size_t)(hh * 32 + fd) * 32;  // wave-uniform -> s_loads
#pragma unroll
            for (int d = 0; d < 32; d++) a += xn[d] * wrow[d];
            a *= scale;
            if (fd & 1) stage[tid][fd >> 1] = ((unsigned int)f2bf(a) << 16) | (unsigned int)f2bf(prev);
            else prev = a;
        }
        __syncthreads();
        // cooperative coalesced store: 256 rows x 64B tile at feature col hh*32
#pragma unroll
        for (int it = 0; it < 4; it++) {
            int rl = (tid >> 2) + it * 64;
            int c = tid & 3;
            uint4 val = *(const uint4*)&stage[rl][c * 4];
            *(uint4*)(dst + (size_t)(rt * 256 + rl) * 256 + hh * 32 + c * 8) = val;
        }
        __syncthreads();
    }
}

// ---------------- fused local attention with RPE bias, bf16 MFMA ----------------
__global__ __launch_bounds__(256) void kattn(
    const unsigned short* qbf, const unsigned short* kbf, const unsigned short* vbf,
    const unsigned int* order, const float* coords, const float* w2,
    unsigned short* aobf)
{
    __shared__ int ord[256];
    __shared__ float pc0[256], pc1[256], ge[256];
    __shared__ unsigned short Kb[256][40];       // K rows, pad 40 (80B stride, 16B aligned)
    __shared__ unsigned short Vt[32][264];       // V transposed [d][j], pad 264 (528B stride)
    __shared__ unsigned short Ps[4][16][264];    // per-wave P strip (C-layout -> A-layout round trip)

    int bh = blockIdx.x;
    int b = bh >> 3, h = bh & 7;
    int tid = threadIdx.x, wave = tid >> 6, lane = tid & 63;
    int col = lane & 15, quad = lane >> 4;
    float w0 = w2[2 * h], w1 = w2[2 * h + 1];

    { // stage sorted rows for this (block, head)
        int i = tid;
        int t = (int)order[b * 256 + i];
        ord[i] = t;
        float a = coords[t * 3 + 1], bb = coords[t * 3 + 2];
        pc0[i] = a; pc1[i] = bb;
        ge[i] = w0 * a * a + w1 * bb * bb;
        const uint4* kr = (const uint4*)(kbf + (size_t)t * 256 + h * 32);
        uint4 k0 = kr[0], k1 = kr[1], k2 = kr[2], k3 = kr[3];
        uint4* kd = (uint4*)&Kb[i][0];
        kd[0] = k0; kd[1] = k1; kd[2] = k2; kd[3] = k3;
        const uint4* vr = (const uint4*)(vbf + (size_t)t * 256 + h * 32);
        uint4 v0 = vr[0], v1 = vr[1], v2 = vr[2], v3 = vr[3];
        unsigned int vws[16] = { v0.x, v0.y, v0.z, v0.w, v1.x, v1.y, v1.z, v1.w,
                                 v2.x, v2.y, v2.z, v2.w, v3.x, v3.y, v3.z, v3.w };
#pragma unroll
        for (int dw = 0; dw < 16; dw++) {
            Vt[dw * 2 + 0][i] = (unsigned short)(vws[dw] & 0xffffu);
            Vt[dw * 2 + 1][i] = (unsigned short)(vws[dw] >> 16);
        }
    }
    __syncthreads();

    // extended-K fragments (bias cross terms), same for all strips of this wave
    bf16x8 keext[16];
#pragma unroll
    for (int nt = 0; nt < 16; nt++) {
        bf16x8 f = { 0, 0, 0, 0, 0, 0, 0, 0 };
        if (quad == 0) {
            int n = nt * 16 + col;
            f[0] = (short)f2bf(pc0[n]);
            f[1] = (short)f2bf(pc1[n]);
            f[2] = (short)f2bf(ge[n]);
        }
        keext[nt] = f;
    }

    for (int si = 0; si < 4; si++) {
        int s = wave * 4 + si;               // strip = rows s*16 .. s*16+15
        int mrow = s * 16 + col;
        int tm = ord[mrow];
        bf16x8 qa = *(const bf16x8*)(qbf + (size_t)tm * 256 + h * 32 + quad * 8);
        bf16x8 qe = { 0, 0, 0, 0, 0, 0, 0, 0 };
        if (quad == 0) {
            qe[0] = (short)f2bf(2.0f * w0 * pc0[mrow]);
            qe[1] = (short)f2bf(2.0f * w1 * pc1[mrow]);
            qe[2] = (short)f2bf(-1.0f);
        }

        f32x4 acc[16];
#pragma unroll
        for (int nt = 0; nt < 16; nt++) {
            int n = nt * 16 + col;
            bf16x8 kb = *(const bf16x8*)&Kb[n][quad * 8];
            f32x4 z = { 0.f, 0.f, 0.f, 0.f };
            z = __builtin_amdgcn_mfma_f32_16x16x32_bf16(qa, kb, z, 0, 0, 0);
            acc[nt] = __builtin_amdgcn_mfma_f32_16x16x32_bf16(qe, keext[nt], z, 0, 0, 0);
        }

        // row-wise softmax: rows live in this wave (C layout: row = quad*4 + reg, col = lane&15)
        float rl[4];
#pragma unroll
        for (int r = 0; r < 4; r++) {
            float m = acc[0][r];
#pragma unroll
            for (int nt = 1; nt < 16; nt++) m = fmaxf(m, acc[nt][r]);
            m = fmaxf(m, __shfl_xor(m, 1));
            m = fmaxf(m, __shfl_xor(m, 2));
            m = fmaxf(m, __shfl_xor(m, 4));
            m = fmaxf(m, __shfl_xor(m, 8));
            float sum = 0.f;
#pragma unroll
            for (int nt = 0; nt < 16; nt++) {
                float e = __expf(acc[nt][r] - m);
                acc[nt][r] = e;
                sum += e;
            }
            sum += __shfl_xor(sum, 1);
            sum += __shfl_xor(sum, 2);
            sum += __shfl_xor(sum, 4);
            sum += __shfl_xor(sum, 8);
            rl[r] = 1.0f / sum;
        }

        // P: C-layout -> LDS (wave-private, no barrier needed)
#pragma unroll
        for (int nt = 0; nt < 16; nt++) {
#pragma unroll
            for (int r = 0; r < 4; r++) {
                Ps[wave][quad * 4 + r][nt * 16 + col] = f2bf(acc[nt][r]);
            }
        }

        // O = P @ V
        f32x4 o0 = { 0.f, 0.f, 0.f, 0.f }, o1 = { 0.f, 0.f, 0.f, 0.f };
#pragma unroll
        for (int ks = 0; ks < 8; ks++) {
            bf16x8 pa  = *(const bf16x8*)&Ps[wave][col][ks * 32 + quad * 8];
            bf16x8 vb0 = *(const bf16x8*)&Vt[col][ks * 32 + quad * 8];
            bf16x8 vb1 = *(const bf16x8*)&Vt[16 + col][ks * 32 + quad * 8];
            o0 = __builtin_amdgcn_mfma_f32_16x16x32_bf16(pa, vb0, o0, 0, 0, 0);
            o1 = __builtin_amdgcn_mfma_f32_16x16x32_bf16(pa, vb1, o1, 0, 0, 0);
        }

        // scale by 1/sum and scatter back to natural token order (bf16)
#pragma unroll
        for (int r = 0; r < 4; r++) {
            int row = s * 16 + quad * 4 + r;
            int t = ord[row];
            unsigned short* dst = aobf + (size_t)t * 256 + h * 32;
            dst[col]      = f2bf(o0[r] * rl[r]);
            dst[16 + col] = f2bf(o1[r] * rl[r]);
        }
    }
}

// ---------------- out-proj + residual + LN2 + FFN + residual ----------------
__global__ __launch_bounds__(256) void kfinal(
    const float* x, const unsigned short* aobf,
    const float* w_out, const float* b_out,
    const float* g2, const float* be2,
    const float* ff_w1, const float* ff_b1, const float* ff_w2, const float* ff_b2,
    float* out)
{
    int row = blockIdx.x * 256 + threadIdx.x;
    const uint4* ao = (const uint4*)(aobf + (size_t)row * 256);

    float aggr[32];
#pragma unroll
    for (int d = 0; d < 32; d++) aggr[d] = 0.f;

    for (int fu = 0; fu < 32; fu++) {       // 8 features per iteration
        uint4 pk = ao[fu];
        float fv[8];
        fv[0] = bf2f((unsigned short)(pk.x & 0xffffu)); fv[1] = bf2f((unsigned short)(pk.x >> 16));
        fv[2] = bf2f((unsigned short)(pk.y & 0xffffu)); fv[3] = bf2f((unsigned short)(pk.y >> 16));
        fv[4] = bf2f((unsigned short)(pk.z & 0xffffu)); fv[5] = bf2f((unsigned short)(pk.z >> 16));
        fv[6] = bf2f((unsigned short)(pk.w & 0xffffu)); fv[7] = bf2f((unsigned short)(pk.w >> 16));
#pragma unroll
        for (int d = 0; d < 32; d++) {
            const float* wr = w_out + (size_t)d * 256 + fu * 8;  // wave-uniform -> s_loads
            float a = aggr[d];
#pragma unroll
            for (int e = 0; e < 8; e++) a += fv[e] * wr[e];
            aggr[d] = a;
        }
    }

    float x2[32];
    const float4* xr = (const float4*)(x + (size_t)row * 32);
#pragma unroll
    for (int q4 = 0; q4 < 8; q4++) {
        float4 t = xr[q4];
        x2[q4 * 4 + 0] = t.x + aggr[q4 * 4 + 0] + b_out[q4 * 4 + 0];
        x2[q4 * 4 + 1] = t.y + aggr[q4 * 4 + 1] + b_out[q4 * 4 + 1];
        x2[q4 * 4 + 2] = t.z + aggr[q4 * 4 + 2] + b_out[q4 * 4 + 2];
        x2[q4 * 4 + 3] = t.w + aggr[q4 * 4 + 3] + b_out[q4 * 4 + 3];
    }

    float mu = 0.f;
#pragma unroll
    for (int d = 0; d < 32; d++) mu += x2[d];
    mu *= (1.0f / 32.0f);
    float var = 0.f;
#pragma unroll
    for (int d = 0; d < 32; d++) { float c = x2[d] - mu; var += c * c; }
    var *= (1.0f / 32.0f);
    float rstd = rsqrtf(var + 1e-5f);
    float xn2[32];
#pragma unroll
    for (int d = 0; d < 32; d++) xn2[d] = (x2[d] - mu) * rstd * g2[d] + be2[d];

    float h1[32];
#pragma unroll
    for (int e = 0; e < 32; e++) {
        float a = ff_b1[e];
#pragma unroll
        for (int d = 0; d < 32; d++) a += xn2[d] * ff_w1[e * 32 + d];
        h1[e] = a > 0.f ? a : 0.f;
    }

    float* op = out + (size_t)row * 32;
#pragma unroll
    for (int q4 = 0; q4 < 8; q4++) {
        float4 o4;
        float r[4];
#pragma unroll
        for (int k = 0; k < 4; k++) {
            int d = q4 * 4 + k;
            float a = ff_b2[d];
#pragma unroll
            for (int e = 0; e < 32; e++) a += h1[e] * ff_w2[d * 32 + e];
            r[k] = x2[d] + a;
        }
        o4.x = r[0]; o4.y = r[1]; o4.z = r[2]; o4.w = r[3];
        ((float4*)op)[q4] = o4;
    }
}

extern "C" void kernel_launch(void* const* d_in, const int* in_sizes, int n_in,
                              void* d_out, int out_size, void* d_ws, size_t ws_size,
                              hipStream_t stream) {
    (void)in_sizes; (void)n_in; (void)out_size; (void)ws_size;
    const float* x      = (const float*)d_in[0];
    const float* coords = (const float*)d_in[1];
    const float* wq     = (const float*)d_in[2];
    const float* wk     = (const float*)d_in[3];
    const float* wv     = (const float*)d_in[4];
    const float* w_rpe  = (const float*)d_in[5];
    const float* w_out  = (const float*)d_in[6];
    const float* b_out  = (const float*)d_in[7];
    const float* g1     = (const float*)d_in[8];
    const float* be1    = (const float*)d_in[9];
    const float* g2     = (const float*)d_in[10];
    const float* be2    = (const float*)d_in[11];
    const float* ffw1   = (const float*)d_in[12];
    const float* ffb1   = (const float*)d_in[13];
    const float* ffw2   = (const float*)d_in[14];
    const float* ffb2   = (const float*)d_in[15];
    float* out = (float*)d_out;

    char* ws = (char*)d_ws;
    unsigned int* hist  = (unsigned int*)ws;   // 65536
    unsigned int* excl  = hist + 65536;        // 65536
    unsigned int* aux   = excl + 65536;        // 256
    unsigned int* memb  = aux + 256;           // 65536
    unsigned int* order = memb + 65536;        // 65536
    float*        w2    = (float*)(order + 65536); // 16
    unsigned short* qbf  = (unsigned short*)(ws + (size_t)(4u)   * 1048576u); // 32 MiB
    unsigned short* kbf  = (unsigned short*)(ws + (size_t)(36u)  * 1048576u); // 32 MiB
    unsigned short* vbf  = (unsigned short*)(ws + (size_t)(68u)  * 1048576u); // 32 MiB
    unsigned short* aobf = (unsigned short*)(ws + (size_t)(100u) * 1048576u); // 32 MiB

    hipMemsetAsync(hist, 0, 65536 * sizeof(unsigned int), stream);
    khist   <<<256, 256, 0, stream>>>(coords, hist);
    kscan1  <<<256, 256, 0, stream>>>(hist, excl, aux);
    kscan2  <<<1,   256, 0, stream>>>(aux);
    kscan3  <<<256, 256, 0, stream>>>(excl, aux);
    kscatter<<<256, 256, 0, stream>>>(coords, excl, memb);
    krank   <<<256, 256, 0, stream>>>(coords, excl, memb, order);
    kw2     <<<16,  256, 0, stream>>>(w_rpe, w2);
    kproj   <<<512, 256, 0, stream>>>(x, g1, be1, wq, wk, wv, qbf, kbf, vbf);
    kattn   <<<2048,256, 0, stream>>>(qbf, kbf, vbf, order, coords, w2, aobf);
    kfinal  <<<256, 256, 0, stream>>>(x, aobf, w_out, b_out, g2, be2, ffw1, ffb1, ffw2, ffb2, out);
}

// Round 2
// 279.215 us; speedup vs baseline: 2.1676x; 2.1676x over previous
//
#include <hip/hip_runtime.h>

#define DEV __device__ __forceinline__

typedef __attribute__((ext_vector_type(8))) short bf16x8;
typedef __attribute__((ext_vector_type(4))) float f32x4;

// problem constants: N=65536 tokens, 8 heads, head dim 32, feature dim 256, block 256
static constexpr float QSCALE = 0.17677669529663687f; // 1/sqrt(32)

DEV unsigned short f2bf(float f) {
    union { float f; unsigned int u; } a; a.f = f;
    unsigned int r = (a.u + 0x7fffu + ((a.u >> 16) & 1u)) >> 16; // RNE
    return (unsigned short)r;
}
DEV float bf2f(unsigned short s) {
    union { unsigned int u; float f; } a; a.u = ((unsigned int)s) << 16;
    return a.f;
}
DEV int bucketof(float v) {
    int b = (int)(v * 65536.0f);
    b = b < 0 ? 0 : b;
    b = b > 65535 ? 65535 : b;
    return b;
}

// ---------------- sort: stable argsort of coords[:,0] ----------------
__global__ void khist(const float* coords, unsigned int* hist) {
    int i = blockIdx.x * 256 + threadIdx.x;
    atomicAdd(&hist[bucketof(coords[i * 3])], 1u);
}

__global__ void kscan1(const unsigned int* hist, unsigned int* excl, unsigned int* aux) {
    __shared__ unsigned int s[256];
    int tid = threadIdx.x;
    int g = blockIdx.x * 256 + tid;
    unsigned int v = hist[g];
    s[tid] = v; __syncthreads();
    for (int off = 1; off < 256; off <<= 1) {
        unsigned int t = (tid >= off) ? s[tid - off] : 0u;
        __syncthreads();
        s[tid] += t;
        __syncthreads();
    }
    excl[g] = s[tid] - v;
    if (tid == 255) aux[blockIdx.x] = s[255];
}

__global__ void kscan2(unsigned int* aux) {
    __shared__ unsigned int s[256];
    int tid = threadIdx.x;
    unsigned int v = aux[tid];
    s[tid] = v; __syncthreads();
    for (int off = 1; off < 256; off <<= 1) {
        unsigned int t = (tid >= off) ? s[tid - off] : 0u;
        __syncthreads();
        s[tid] += t;
        __syncthreads();
    }
    aux[tid] = s[tid] - v;
}

__global__ void kscan3(unsigned int* excl, const unsigned int* aux) {
    int g = blockIdx.x * 256 + threadIdx.x;
    excl[g] += aux[blockIdx.x];
}

__global__ void kscatter(const float* coords, unsigned int* excl, unsigned int* memb) {
    int i = blockIdx.x * 256 + threadIdx.x;
    int b = bucketof(coords[i * 3]);
    unsigned int pos = atomicAdd(&excl[b], 1u);
    memb[pos] = (unsigned int)i;
}

__global__ void krank(const float* coords, const unsigned int* excl,
                      const unsigned int* memb, unsigned int* order) {
    int i = blockIdx.x * 256 + threadIdx.x;
    int b = bucketof(coords[i * 3]);
    unsigned int start = (b == 0) ? 0u : excl[b - 1];
    unsigned int end = excl[b];
    unsigned int ki = __float_as_uint(coords[i * 3]);
    unsigned int r = start;
    for (unsigned int s2 = start; s2 < end; ++s2) {
        unsigned int j = memb[s2];
        unsigned int kj = __float_as_uint(coords[j * 3]);
        if (kj < ki || (kj == ki && j < (unsigned int)i)) r++;
    }
    order[r] = (unsigned int)i;
}

// ---------------- w2[h][c] = mean over (d,j) of w_rpe[h*32+d][c*8+j]^2 ----------------
__global__ void kw2(const float* w_rpe, float* w2) {
    int p = blockIdx.x;
    int h = p >> 1, c = p & 1;
    int tid = threadIdx.x;
    int d = tid >> 3, j = tid & 7;
    float v = w_rpe[(h * 32 + d) * 16 + c * 8 + j];
    float v2 = v * v;
    for (int m = 32; m >= 1; m >>= 1) v2 += __shfl_xor(v2, m);
    __shared__ float part[4];
    if ((tid & 63) == 0) part[tid >> 6] = v2;
    __syncthreads();
    if (tid == 0) w2[p] = (part[0] + part[1] + part[2] + part[3]) * (1.0f / 256.0f);
}

// ---------------- weight prep: fp32 -> bf16 (QSCALE folded into wq) ----------------
// wqkvb [768][32]: rows 0-255 wq*QSCALE, 256-511 wk, 512-767 wv
// woutb [32][256], ff1b [32][32], ff2b [32][32] (natural row-major)
__global__ void kwprep(const float* wq, const float* wk, const float* wv,
                       const float* w_out, const float* ff1, const float* ff2,
                       unsigned short* wqkvb, unsigned short* woutb,
                       unsigned short* ff1b, unsigned short* ff2b) {
    int i = blockIdx.x * 256 + threadIdx.x;   // 136*256 = 34816 elems
    if (i < 8192)        wqkvb[i] = f2bf(wq[i] * QSCALE);
    else if (i < 16384)  wqkvb[i] = f2bf(wk[i - 8192]);
    else if (i < 24576)  wqkvb[i] = f2bf(wv[i - 16384]);
    else if (i < 32768)  woutb[i - 24576] = f2bf(w_out[i - 24576]);
    else if (i < 33792)  ff1b[i - 32768] = f2bf(ff1[i - 32768]);
    else                 ff2b[i - 33792] = f2bf(ff2[i - 33792]);
}

// ---------------- LN1 + QKV projection via MFMA -> bf16 [N][256] ----------------
// grid 512, 128 rows/block. A = LN(x) bf16 (LDS), B = wqkvb. K=32 -> 1 MFMA/tile.
__global__ __launch_bounds__(256) void kproj(
    const float* x, const float* g1, const float* be1,
    const unsigned short* wqkvb,
    unsigned short* qbf, unsigned short* kbf, unsigned short* vbf)
{
    __shared__ unsigned short xnb[128][40];    // 10 KB, 80B row stride (16B aligned)
    __shared__ unsigned short stage[16][776];  // 24.25 KB output staging per row tile
    int tid = threadIdx.x;
    int base = blockIdx.x * 128;

    if (tid < 128) {
        int row = base + tid;
        float xv[32];
        const float4* xr = (const float4*)(x + (size_t)row * 32);
#pragma unroll
        for (int q4 = 0; q4 < 8; q4++) {
            float4 t = xr[q4];
            xv[q4 * 4 + 0] = t.x; xv[q4 * 4 + 1] = t.y; xv[q4 * 4 + 2] = t.z; xv[q4 * 4 + 3] = t.w;
        }
        float mu = 0.f;
#pragma unroll
        for (int d = 0; d < 32; d++) mu += xv[d];
        mu *= (1.0f / 32.0f);
        float var = 0.f;
#pragma unroll
        for (int d = 0; d < 32; d++) { float c = xv[d] - mu; var += c * c; }
        var *= (1.0f / 32.0f);
        float rstd = rsqrtf(var + 1e-5f);
        unsigned int pk[16];
#pragma unroll
        for (int w = 0; w < 16; w++) {
            float a = (xv[2 * w] - mu) * rstd * g1[2 * w] + be1[2 * w];
            float b = (xv[2 * w + 1] - mu) * rstd * g1[2 * w + 1] + be1[2 * w + 1];
            pk[w] = ((unsigned int)f2bf(b) << 16) | (unsigned int)f2bf(a);
        }
        uint4* dst = (uint4*)&xnb[tid][0];
#pragma unroll
        for (int w4 = 0; w4 < 4; w4++) {
            uint4 v; v.x = pk[w4*4]; v.y = pk[w4*4+1]; v.z = pk[w4*4+2]; v.w = pk[w4*4+3];
            dst[w4] = v;
        }
    }
    __syncthreads();

    int wave = tid >> 6, lane = tid & 63, col = lane & 15, quad = lane >> 4;

    // preload this wave's 12 B-fragments (col tiles ct = j*4+wave)
    bf16x8 bfrag[12];
#pragma unroll
    for (int j = 0; j < 12; j++) {
        int o = (j * 4 + wave) * 16 + col;
        bfrag[j] = *(const bf16x8*)(wqkvb + (size_t)o * 32 + quad * 8);
    }

    for (int rt = 0; rt < 8; rt++) {
        bf16x8 af = *(const bf16x8*)&xnb[rt * 16 + col][quad * 8];
#pragma unroll
        for (int j = 0; j < 12; j++) {
            int ct = j * 4 + wave;
            f32x4 z = { 0.f, 0.f, 0.f, 0.f };
            z = __builtin_amdgcn_mfma_f32_16x16x32_bf16(af, bfrag[j], z, 0, 0, 0);
#pragma unroll
            for (int r = 0; r < 4; r++) stage[quad * 4 + r][ct * 16 + col] = f2bf(z[r]);
        }
        __syncthreads();
        // coalesced store: 16 rows x 768 bf16 -> q/k/v
#pragma unroll
        for (int it = 0; it < 6; it++) {
            int u = it * 256 + tid;
            int r = u / 96, c16 = u % 96;
            int bufsel = c16 >> 5;
            int cw = c16 & 31;
            uint4 val = *(const uint4*)&stage[r][c16 * 8];
            unsigned short* dstp = bufsel == 0 ? qbf : (bufsel == 1 ? kbf : vbf);
            *(uint4*)(dstp + (size_t)(base + rt * 16 + r) * 256 + cw * 8) = val;
        }
        __syncthreads();
    }
}

// ---------------- fused local attention with RPE bias, bf16 MFMA (unchanged) ----------------
__global__ __launch_bounds__(256) void kattn(
    const unsigned short* qbf, const unsigned short* kbf, const unsigned short* vbf,
    const unsigned int* order, const float* coords, const float* w2,
    unsigned short* aobf)
{
    __shared__ int ord[256];
    __shared__ float pc0[256], pc1[256], ge[256];
    __shared__ unsigned short Kb[256][40];
    __shared__ unsigned short Vt[32][264];
    __shared__ unsigned short Ps[4][16][264];

    int bh = blockIdx.x;
    int b = bh >> 3, h = bh & 7;
    int tid = threadIdx.x, wave = tid >> 6, lane = tid & 63;
    int col = lane & 15, quad = lane >> 4;
    float w0 = w2[2 * h], w1 = w2[2 * h + 1];

    {
        int i = tid;
        int t = (int)order[b * 256 + i];
        ord[i] = t;
        float a = coords[t * 3 + 1], bb = coords[t * 3 + 2];
        pc0[i] = a; pc1[i] = bb;
        ge[i] = w0 * a * a + w1 * bb * bb;
        const uint4* kr = (const uint4*)(kbf + (size_t)t * 256 + h * 32);
        uint4 k0 = kr[0], k1 = kr[1], k2 = kr[2], k3 = kr[3];
        uint4* kd = (uint4*)&Kb[i][0];
        kd[0] = k0; kd[1] = k1; kd[2] = k2; kd[3] = k3;
        const uint4* vr = (const uint4*)(vbf + (size_t)t * 256 + h * 32);
        uint4 v0 = vr[0], v1 = vr[1], v2 = vr[2], v3 = vr[3];
        unsigned int vws[16] = { v0.x, v0.y, v0.z, v0.w, v1.x, v1.y, v1.z, v1.w,
                                 v2.x, v2.y, v2.z, v2.w, v3.x, v3.y, v3.z, v3.w };
#pragma unroll
        for (int dw = 0; dw < 16; dw++) {
            Vt[dw * 2 + 0][i] = (unsigned short)(vws[dw] & 0xffffu);
            Vt[dw * 2 + 1][i] = (unsigned short)(vws[dw] >> 16);
        }
    }
    __syncthreads();

    bf16x8 keext[16];
#pragma unroll
    for (int nt = 0; nt < 16; nt++) {
        bf16x8 f = { 0, 0, 0, 0, 0, 0, 0, 0 };
        if (quad == 0) {
            int n = nt * 16 + col;
            f[0] = (short)f2bf(pc0[n]);
            f[1] = (short)f2bf(pc1[n]);
            f[2] = (short)f2bf(ge[n]);
        }
        keext[nt] = f;
    }

    for (int si = 0; si < 4; si++) {
        int s = wave * 4 + si;
        int mrow = s * 16 + col;
        int tm = ord[mrow];
        bf16x8 qa = *(const bf16x8*)(qbf + (size_t)tm * 256 + h * 32 + quad * 8);
        bf16x8 qe = { 0, 0, 0, 0, 0, 0, 0, 0 };
        if (quad == 0) {
            qe[0] = (short)f2bf(2.0f * w0 * pc0[mrow]);
            qe[1] = (short)f2bf(2.0f * w1 * pc1[mrow]);
            qe[2] = (short)f2bf(-1.0f);
        }

        f32x4 acc[16];
#pragma unroll
        for (int nt = 0; nt < 16; nt++) {
            int n = nt * 16 + col;
            bf16x8 kb = *(const bf16x8*)&Kb[n][quad * 8];
            f32x4 z = { 0.f, 0.f, 0.f, 0.f };
            z = __builtin_amdgcn_mfma_f32_16x16x32_bf16(qa, kb, z, 0, 0, 0);
            acc[nt] = __builtin_amdgcn_mfma_f32_16x16x32_bf16(qe, keext[nt], z, 0, 0, 0);
        }

        float rl[4];
#pragma unroll
        for (int r = 0; r < 4; r++) {
            float m = acc[0][r];
#pragma unroll
            for (int nt = 1; nt < 16; nt++) m = fmaxf(m, acc[nt][r]);
            m = fmaxf(m, __shfl_xor(m, 1));
            m = fmaxf(m, __shfl_xor(m, 2));
            m = fmaxf(m, __shfl_xor(m, 4));
            m = fmaxf(m, __shfl_xor(m, 8));
            float sum = 0.f;
#pragma unroll
            for (int nt = 0; nt < 16; nt++) {
                float e = __expf(acc[nt][r] - m);
                acc[nt][r] = e;
                sum += e;
            }
            sum += __shfl_xor(sum, 1);
            sum += __shfl_xor(sum, 2);
            sum += __shfl_xor(sum, 4);
            sum += __shfl_xor(sum, 8);
            rl[r] = 1.0f / sum;
        }

#pragma unroll
        for (int nt = 0; nt < 16; nt++) {
#pragma unroll
            for (int r = 0; r < 4; r++) {
                Ps[wave][quad * 4 + r][nt * 16 + col] = f2bf(acc[nt][r]);
            }
        }

        f32x4 o0 = { 0.f, 0.f, 0.f, 0.f }, o1 = { 0.f, 0.f, 0.f, 0.f };
#pragma unroll
        for (int ks = 0; ks < 8; ks++) {
            bf16x8 pa  = *(const bf16x8*)&Ps[wave][col][ks * 32 + quad * 8];
            bf16x8 vb0 = *(const bf16x8*)&Vt[col][ks * 32 + quad * 8];
            bf16x8 vb1 = *(const bf16x8*)&Vt[16 + col][ks * 32 + quad * 8];
            o0 = __builtin_amdgcn_mfma_f32_16x16x32_bf16(pa, vb0, o0, 0, 0, 0);
            o1 = __builtin_amdgcn_mfma_f32_16x16x32_bf16(pa, vb1, o1, 0, 0, 0);
        }

#pragma unroll
        for (int r = 0; r < 4; r++) {
            int row = s * 16 + quad * 4 + r;
            int t = ord[row];
            unsigned short* dst = aobf + (size_t)t * 256 + h * 32;
            dst[col]      = f2bf(o0[r] * rl[r]);
            dst[16 + col] = f2bf(o1[r] * rl[r]);
        }
    }
}

// ---------------- out-proj + residual + LN2 + FFN + residual, all MFMA ----------------
// grid 512, 128 rows/block, wave handles 2 row tiles of 16.
__global__ __launch_bounds__(256) void kfinal(
    const float* x, const unsigned short* aobf,
    const unsigned short* woutb, const float* b_out,
    const float* g2, const float* be2,
    const unsigned short* ff1b, const float* ffb1,
    const unsigned short* ff2b, const float* ffb2,
    float* out)
{
    __shared__ unsigned short strip[4][16][40];  // per-wave C->A layout round trip
    int tid = threadIdx.x;
    int wave = tid >> 6, lane = tid & 63, col = lane & 15, quad = lane >> 4;
    int base = blockIdx.x * 128;

    // preload B fragments (L1-resident weights)
    bf16x8 wof[16];
#pragma unroll
    for (int ct = 0; ct < 2; ct++)
#pragma unroll
        for (int ks = 0; ks < 8; ks++)
            wof[ct * 8 + ks] = *(const bf16x8*)(woutb + (size_t)(ct * 16 + col) * 256 + ks * 32 + quad * 8);
    bf16x8 w1f[2], w2f[2];
#pragma unroll
    for (int ct = 0; ct < 2; ct++) {
        w1f[ct] = *(const bf16x8*)(ff1b + (ct * 16 + col) * 32 + quad * 8);
        w2f[ct] = *(const bf16x8*)(ff2b + (ct * 16 + col) * 32 + quad * 8);
    }
    float bo0 = b_out[col], bo1 = b_out[col + 16];
    float g20 = g2[col], g21 = g2[col + 16], be20 = be2[col], be21 = be2[col + 16];
    float fb10 = ffb1[col], fb11 = ffb1[col + 16];
    float fb20 = ffb2[col], fb21 = ffb2[col + 16];

    for (int rr = 0; rr < 2; rr++) {
        int rt = wave * 2 + rr;
        int row0 = base + rt * 16;

        // out-proj: aggr = ao @ w_out.T, K=256 (8 MFMAs)
        f32x4 a0 = { 0.f, 0.f, 0.f, 0.f }, a1 = { 0.f, 0.f, 0.f, 0.f };
        const unsigned short* arow = aobf + (size_t)(row0 + col) * 256;
#pragma unroll
        for (int ks = 0; ks < 8; ks++) {
            bf16x8 af = *(const bf16x8*)(arow + ks * 32 + quad * 8);
            a0 = __builtin_amdgcn_mfma_f32_16x16x32_bf16(af, wof[ks], a0, 0, 0, 0);
            a1 = __builtin_amdgcn_mfma_f32_16x16x32_bf16(af, wof[8 + ks], a1, 0, 0, 0);
        }

        // x2 = x + aggr + b_out (C layout: row=quad*4+r, cols col / col+16)
#pragma unroll
        for (int r = 0; r < 4; r++) {
            int row = row0 + quad * 4 + r;
            a0[r] += x[(size_t)row * 32 + col] + bo0;
            a1[r] += x[(size_t)row * 32 + 16 + col] + bo1;
        }

        // LN2 row-wise over the 16-lane group
        f32x4 xn0, xn1;
#pragma unroll
        for (int r = 0; r < 4; r++) {
            float s = a0[r] + a1[r];
            s += __shfl_xor(s, 1); s += __shfl_xor(s, 2); s += __shfl_xor(s, 4); s += __shfl_xor(s, 8);
            float mu = s * (1.0f / 32.0f);
            float c0 = a0[r] - mu, c1 = a1[r] - mu;
            float v = c0 * c0 + c1 * c1;
            v += __shfl_xor(v, 1); v += __shfl_xor(v, 2); v += __shfl_xor(v, 4); v += __shfl_xor(v, 8);
            float rstd = rsqrtf(v * (1.0f / 32.0f) + 1e-5f);
            xn0[r] = c0 * rstd * g20 + be20;
            xn1[r] = c1 * rstd * g21 + be21;
        }

        // C->A round trip 1 (wave-private)
#pragma unroll
        for (int r = 0; r < 4; r++) {
            strip[wave][quad * 4 + r][col]      = f2bf(xn0[r]);
            strip[wave][quad * 4 + r][col + 16] = f2bf(xn1[r]);
        }
        bf16x8 af1 = *(const bf16x8*)&strip[wave][col][quad * 8];
        f32x4 z = { 0.f, 0.f, 0.f, 0.f };
        f32x4 h0 = __builtin_amdgcn_mfma_f32_16x16x32_bf16(af1, w1f[0], z, 0, 0, 0);
        f32x4 h1 = __builtin_amdgcn_mfma_f32_16x16x32_bf16(af1, w1f[1], z, 0, 0, 0);
#pragma unroll
        for (int r = 0; r < 4; r++) {
            h0[r] = fmaxf(h0[r] + fb10, 0.f);
            h1[r] = fmaxf(h1[r] + fb11, 0.f);
        }

        // C->A round trip 2
#pragma unroll
        for (int r = 0; r < 4; r++) {
            strip[wave][quad * 4 + r][col]      = f2bf(h0[r]);
            strip[wave][quad * 4 + r][col + 16] = f2bf(h1[r]);
        }
        bf16x8 af2 = *(const bf16x8*)&strip[wave][col][quad * 8];
        f32x4 f0 = __builtin_amdgcn_mfma_f32_16x16x32_bf16(af2, w2f[0], z, 0, 0, 0);
        f32x4 f1 = __builtin_amdgcn_mfma_f32_16x16x32_bf16(af2, w2f[1], z, 0, 0, 0);

#pragma unroll
        for (int r = 0; r < 4; r++) {
            int row = row0 + quad * 4 + r;
            out[(size_t)row * 32 + col]      = a0[r] + f0[r] + fb20;
            out[(size_t)row * 32 + 16 + col] = a1[r] + f1[r] + fb21;
        }
    }
}

extern "C" void kernel_launch(void* const* d_in, const int* in_sizes, int n_in,
                              void* d_out, int out_size, void* d_ws, size_t ws_size,
                              hipStream_t stream) {
    (void)in_sizes; (void)n_in; (void)out_size; (void)ws_size;
    const float* x      = (const float*)d_in[0];
    const float* coords = (const float*)d_in[1];
    const float* wq     = (const float*)d_in[2];
    const float* wk     = (const float*)d_in[3];
    const float* wv     = (const float*)d_in[4];
    const float* w_rpe  = (const float*)d_in[5];
    const float* w_out  = (const float*)d_in[6];
    const float* b_out  = (const float*)d_in[7];
    const float* g1     = (const float*)d_in[8];
    const float* be1    = (const float*)d_in[9];
    const float* g2     = (const float*)d_in[10];
    const float* be2    = (const float*)d_in[11];
    const float* ffw1   = (const float*)d_in[12];
    const float* ffb1   = (const float*)d_in[13];
    const float* ffw2   = (const float*)d_in[14];
    const float* ffb2   = (const float*)d_in[15];
    float* out = (float*)d_out;

    char* ws = (char*)d_ws;
    unsigned int* hist  = (unsigned int*)ws;   // 65536
    unsigned int* excl  = hist + 65536;        // 65536
    unsigned int* aux   = excl + 65536;        // 256
    unsigned int* memb  = aux + 256;           // 65536
    unsigned int* order = memb + 65536;        // 65536
    float*        w2    = (float*)(order + 65536); // 16
    unsigned short* wqkvb = (unsigned short*)(ws + (size_t)2 * 1048576); // 48 KB
    unsigned short* woutb = wqkvb + 24576;                              // 16 KB
    unsigned short* ff1b  = woutb + 8192;
    unsigned short* ff2b  = ff1b + 1024;
    unsigned short* qbf  = (unsigned short*)(ws + (size_t)4   * 1048576); // 32 MiB
    unsigned short* kbf  = (unsigned short*)(ws + (size_t)36  * 1048576); // 32 MiB
    unsigned short* vbf  = (unsigned short*)(ws + (size_t)68  * 1048576); // 32 MiB
    unsigned short* aobf = (unsigned short*)(ws + (size_t)100 * 1048576); // 32 MiB

    hipMemsetAsync(hist, 0, 65536 * sizeof(unsigned int), stream);
    khist   <<<256, 256, 0, stream>>>(coords, hist);
    kscan1  <<<256, 256, 0, stream>>>(hist, excl, aux);
    kscan2  <<<1,   256, 0, stream>>>(aux);
    kscan3  <<<256, 256, 0, stream>>>(excl, aux);
    kscatter<<<256, 256, 0, stream>>>(coords, excl, memb);
    krank   <<<256, 256, 0, stream>>>(coords, excl, memb, order);
    kw2     <<<16,  256, 0, stream>>>(w_rpe, w2);
    kwprep  <<<136, 256, 0, stream>>>(wq, wk, wv, w_out, ffw1, ffw2, wqkvb, woutb, ff1b, ff2b);
    kproj   <<<512, 256, 0, stream>>>(x, g1, be1, wqkvb, qbf, kbf, vbf);
    kattn   <<<2048,256, 0, stream>>>(qbf, kbf, vbf, order, coords, w2, aobf);
    kfinal  <<<512, 256, 0, stream>>>(x, aobf, woutb, b_out, g2, be2, ff1b, ffb1, ff2b, ffb2, out);
}